// Round 3
// baseline (3158.634 us; speedup 1.0000x reference)
//
#include <hip/hip_runtime.h>
#include <hip/hip_bf16.h>

#define TT    128
#define BATCH 1024
#define INDIM 512
#define HIDD  1024
#define NCLS  10

typedef __bf16 bf16x8 __attribute__((ext_vector_type(8)));
typedef float  f32x4  __attribute__((ext_vector_type(4)));
typedef unsigned short u16x8 __attribute__((ext_vector_type(8)));

__device__ __forceinline__ unsigned short bf16b(float f) {
    __hip_bfloat16 h = __float2bfloat16(f);
    return __builtin_bit_cast(unsigned short, h);
}

__device__ __forceinline__ float tanh_fast(float x) {
    float e = __expf(2.0f * x);
    return 1.0f - 2.0f * __builtin_amdgcn_rcpf(e + 1.0f);
}

// ---------------------------------------------------------------------------
// Prep: W -> transposed bf16 hi/lo pairs (unchanged, verified R1/R2).
// ---------------------------------------------------------------------------
__global__ __launch_bounds__(256) void prep_kernel(
    const float* __restrict__ Whh, const float* __restrict__ Wxh,
    __hip_bfloat16* __restrict__ WhhT_hi, __hip_bfloat16* __restrict__ WhhT_lo,
    __hip_bfloat16* __restrict__ WxhT_hi, __hip_bfloat16* __restrict__ WxhT_lo)
{
    __shared__ float tl[64][68];
    int bid = blockIdx.x, tid = threadIdx.x;
    const float* src; int N, k0, n0, dstride;
    __hip_bfloat16 *dhi, *dlo;
    if (bid < 256) { src = Whh; N = 1024; k0 = (bid >> 4) << 6; n0 = (bid & 15) << 6;
                     dhi = WhhT_hi; dlo = WhhT_lo; dstride = 1024; }
    else { int b = bid - 256; src = Wxh; N = 1024; k0 = (b >> 4) << 6; n0 = (b & 15) << 6;
           dhi = WxhT_hi; dlo = WxhT_lo; dstride = 512; }

    int r = tid >> 2, c0 = (tid & 3) << 4;
    const float* s = src + (size_t)(k0 + r) * N + n0 + c0;
#pragma unroll
    for (int j = 0; j < 4; ++j)
        *(float4*)&tl[r][c0 + j * 4] = *(const float4*)(s + j * 4);
    __syncthreads();

    int rn = tid >> 2, ck0 = (tid & 3) << 4;
    u16x8 hi0, hi1, lo0, lo1;
#pragma unroll
    for (int j = 0; j < 16; ++j) {
        float w = tl[ck0 + j][rn];
        unsigned short hb = bf16b(w);
        float hf = __bfloat162float(__builtin_bit_cast(__hip_bfloat16, hb));
        unsigned short lb = bf16b(w - hf);
        if (j < 8) { hi0[j] = hb; lo0[j] = lb; }
        else       { hi1[j - 8] = hb; lo1[j - 8] = lb; }
    }
    size_t o = (size_t)(n0 + rn) * dstride + k0 + ck0;
    *(u16x8*)(void*)(dhi + o)     = hi0;
    *(u16x8*)(void*)(dhi + o + 8) = hi1;
    *(u16x8*)(void*)(dlo + o)     = lo0;
    *(u16x8*)(void*)(dlo + o + 8) = lo1;
}

// ---------------------------------------------------------------------------
// Convert ALL of x: [b][t][512] f32 -> xs [t][b][512] bf16 (one pass, 60us).
// ---------------------------------------------------------------------------
__global__ __launch_bounds__(256) void convx_all_kernel(
    const float* __restrict__ x, __hip_bfloat16* __restrict__ xs)
{
    size_t gid = (size_t)blockIdx.x * 256 + threadIdx.x;
    int i  = (int)(gid & 63) << 3;          // 64 x 8 elems = 512
    size_t bt = gid >> 6;
    int t = (int)(bt & 127);
    int b = (int)(bt >> 7);
    const float* s = x + ((size_t)b * TT + t) * INDIM + i;
    float4 a0 = *(const float4*)s, a1 = *(const float4*)(s + 4);
    u16x8 o;
    o[0]=bf16b(a0.x); o[1]=bf16b(a0.y); o[2]=bf16b(a0.z); o[3]=bf16b(a0.w);
    o[4]=bf16b(a1.x); o[5]=bf16b(a1.y); o[6]=bf16b(a1.z); o[7]=bf16b(a1.w);
    *(u16x8*)(void*)(xs + ((size_t)t * BATCH + b) * INDIM + i) = o;
}

// Zero h0 (blocks 0..511) and the barrier counters (block 512).
__global__ __launch_bounds__(256) void zero_kernel(
    __hip_bfloat16* __restrict__ h, unsigned* __restrict__ bar)
{
    if (blockIdx.x < 512) {
        size_t i = ((size_t)blockIdx.x * 256 + threadIdx.x) << 3;
        u16x8 z = {0,0,0,0,0,0,0,0};
        *(u16x8*)(void*)(h + i) = z;
    } else {
        uint4 z = {0,0,0,0};
        ((uint4*)bar)[threadIdx.x] = z;     // 4KB
    }
}

// ---------------------------------------------------------------------------
// Persistent RNN kernel. 256 blocks x 256 threads, 1 block/CU (forced by
// VGPR use). Wave w of block (bx,by) owns output cols [bx*64+w*16, +16),
// rows [by*64, +64). B fragments (hi+lo, full K=1536) live in 384 VGPRs for
// all 128 steps. A (h rows + x rows) staged per 128-K chunk via
// global_load_lds, XOR-swizzled, double-buffered. Steps separated by
// 16-block group barriers (blocks sharing `by`), with agent fences.
// ---------------------------------------------------------------------------
__global__ __launch_bounds__(256, 1) void rnn_kernel(
    __hip_bfloat16* __restrict__ h0, __hip_bfloat16* __restrict__ h1,
    const __hip_bfloat16* __restrict__ xs,
    const __hip_bfloat16* __restrict__ WhhT_hi, const __hip_bfloat16* __restrict__ WhhT_lo,
    const __hip_bfloat16* __restrict__ WxhT_hi, const __hip_bfloat16* __restrict__ WxhT_lo,
    const float* __restrict__ b_xh, const float* __restrict__ b_hh,
    unsigned* __restrict__ bar)
{
    __shared__ char smem[32768];                 // 2 x 16KB A-chunk buffers
    int tid = threadIdx.x, bid = blockIdx.x;
    int xcd = bid & 7, idx = bid >> 3;
    int bx = (xcd << 1) | (idx >> 4), by = idx & 15;
    int lane = tid & 63, wave = tid >> 6;
    int ar = lane & 15, kg = lane >> 4;
    int wcol = (bx << 6) + (wave << 4);
    int by64 = by << 6;

    // ---- load this wave's B fragments into registers: 96 x bf16x8 ----
    bf16x8 Bf[96];
    {
        const __hip_bfloat16* hiB = WhhT_hi + (size_t)(wcol + ar) * HIDD + (kg << 3);
        const __hip_bfloat16* loB = WhhT_lo + (size_t)(wcol + ar) * HIDD + (kg << 3);
#pragma unroll
        for (int c = 0; c < 8; ++c)
#pragma unroll
            for (int ks = 0; ks < 4; ++ks) {
                Bf[c*8 + ks*2 + 0] = *(const bf16x8*)(hiB + c*128 + ks*32);
                Bf[c*8 + ks*2 + 1] = *(const bf16x8*)(loB + c*128 + ks*32);
            }
        const __hip_bfloat16* hiX = WxhT_hi + (size_t)(wcol + ar) * INDIM + (kg << 3);
        const __hip_bfloat16* loX = WxhT_lo + (size_t)(wcol + ar) * INDIM + (kg << 3);
#pragma unroll
        for (int c = 0; c < 4; ++c)
#pragma unroll
            for (int ks = 0; ks < 4; ++ks) {
                Bf[64 + c*8 + ks*2 + 0] = *(const bf16x8*)(hiX + c*128 + ks*32);
                Bf[64 + c*8 + ks*2 + 1] = *(const bf16x8*)(loX + c*128 + ks*32);
            }
    }

    int mycol = wcol + ar;
    float bias = b_xh[mycol] + b_hh[mycol];
    unsigned* mybar = bar + (by << 5);           // 128B-padded counters

    for (int t = 0; t < TT; ++t) {
        const __hip_bfloat16* hA = (t & 1) ? h1 : h0;
        __hip_bfloat16*       hB = (t & 1) ? h0 : h1;
        const __hip_bfloat16* xsl = xs + (size_t)t * (BATCH * INDIM);

        // Stage A chunk c (64 rows x 128 K, 16KB) into smem buffer bufsel.
        // LDS slot s holds data slot s ^ (row&7)  (swizzle via source addr).
        auto stage = [&](int bufsel, int c) {
            const __hip_bfloat16* base; int rs;
            if (c < 8) { base = hA  + (size_t)by64 * HIDD  + (c << 7);       rs = HIDD;  }
            else       { base = xsl + (size_t)by64 * INDIM + ((c - 8) << 7); rs = INDIM; }
#pragma unroll
            for (int i = 0; i < 4; ++i) {
                int r = (i << 4) + (tid >> 4);
                int s = (tid & 15) ^ (r & 7);
                const void* g = (const void*)(base + (size_t)r * rs + (s << 3));
                void* l = (void*)(smem + bufsel * 16384 + (i << 12) + (wave << 10));
                __builtin_amdgcn_global_load_lds(
                    (const __attribute__((address_space(1))) void*)g,
                    (__attribute__((address_space(3))) void*)l, 16, 0, 0);
            }
        };
        auto fragA = [&](const char* buf, int m, int ks) -> bf16x8 {
            int row  = (m << 4) + ar;
            int slot = ((ks << 2) + kg) ^ (row & 7);
            return *(const bf16x8*)(buf + (row << 8) + (slot << 4));
        };

        f32x4 acc0 = {0,0,0,0}, acc1 = {0,0,0,0}, acc2 = {0,0,0,0}, acc3 = {0,0,0,0};

        stage(0, 0);
        __syncthreads();
#pragma unroll
        for (int c = 0; c < 12; ++c) {
            const char* cur = smem + (c & 1) * 16384;
            if (c < 11) stage((c + 1) & 1, c + 1);
#pragma unroll
            for (int ks = 0; ks < 4; ++ks) {
                bf16x8 a0 = fragA(cur, 0, ks);
                bf16x8 a1 = fragA(cur, 1, ks);
                bf16x8 a2 = fragA(cur, 2, ks);
                bf16x8 a3 = fragA(cur, 3, ks);
                int ib = c * 8 + ks * 2;
                acc0 = __builtin_amdgcn_mfma_f32_16x16x32_bf16(a0, Bf[ib],     acc0, 0, 0, 0);
                acc0 = __builtin_amdgcn_mfma_f32_16x16x32_bf16(a0, Bf[ib + 1], acc0, 0, 0, 0);
                acc1 = __builtin_amdgcn_mfma_f32_16x16x32_bf16(a1, Bf[ib],     acc1, 0, 0, 0);
                acc1 = __builtin_amdgcn_mfma_f32_16x16x32_bf16(a1, Bf[ib + 1], acc1, 0, 0, 0);
                acc2 = __builtin_amdgcn_mfma_f32_16x16x32_bf16(a2, Bf[ib],     acc2, 0, 0, 0);
                acc2 = __builtin_amdgcn_mfma_f32_16x16x32_bf16(a2, Bf[ib + 1], acc2, 0, 0, 0);
                acc3 = __builtin_amdgcn_mfma_f32_16x16x32_bf16(a3, Bf[ib],     acc3, 0, 0, 0);
                acc3 = __builtin_amdgcn_mfma_f32_16x16x32_bf16(a3, Bf[ib + 1], acc3, 0, 0, 0);
            }
            __syncthreads();
        }

        // Epilogue: bias + tanh + bf16 store. D: col=lane&15, row=kg*4+j (+m*16).
#pragma unroll
        for (int m = 0; m < 4; ++m) {
            f32x4 a = (m == 0) ? acc0 : (m == 1) ? acc1 : (m == 2) ? acc2 : acc3;
#pragma unroll
            for (int j = 0; j < 4; ++j) {
                int row = by64 + (m << 4) + (kg << 2) + j;
                float v = tanh_fast(a[j] + bias);
                hB[(size_t)row * HIDD + mycol] = __float2bfloat16(v);
            }
        }

        // Group barrier: 16 blocks sharing `by` (the only data dependence).
        if (t < TT - 1) {
            __syncthreads();                      // all stores drained (vmcnt0)
            if (tid == 0) {
                __threadfence();                  // release: wb to coherence point
                atomicAdd(mybar, 1u);
                unsigned target = (unsigned)((t + 1) << 4);
                while (__hip_atomic_load(mybar, __ATOMIC_RELAXED,
                                         __HIP_MEMORY_SCOPE_AGENT) < target)
                    __builtin_amdgcn_s_sleep(1);
                __threadfence();                  // acquire: inv L1/L2 stale lines
            }
            __syncthreads();
        }
    }
}

// ---------------------------------------------------------------------------
__global__ __launch_bounds__(64) void out_kernel(
    const __hip_bfloat16* __restrict__ h, const float* __restrict__ Why,
    const float* __restrict__ b_y, float* __restrict__ out)
{
    int b = blockIdx.x, lane = threadIdx.x;
    float acc[NCLS];
#pragma unroll
    for (int c = 0; c < NCLS; ++c) acc[c] = 0.f;
    for (int kk = 0; kk < 16; ++kk) {
        int k = (kk << 6) + lane;
        float hv = __bfloat162float(h[(size_t)b * HIDD + k]);
#pragma unroll
        for (int c = 0; c < NCLS; ++c) acc[c] += hv * Why[(size_t)k * NCLS + c];
    }
#pragma unroll
    for (int c = 0; c < NCLS; ++c) {
        float v = acc[c];
#pragma unroll
        for (int off = 32; off > 0; off >>= 1) v += __shfl_down(v, off);
        if (lane == 0) out[(size_t)b * NCLS + c] = v + b_y[c];
    }
}

// ---------------------------------------------------------------------------
extern "C" void kernel_launch(void* const* d_in, const int* in_sizes, int n_in,
                              void* d_out, int out_size, void* d_ws, size_t ws_size,
                              hipStream_t stream)
{
    const float* x    = (const float*)d_in[0];
    const float* Wxh  = (const float*)d_in[1];
    const float* b_xh = (const float*)d_in[2];
    const float* Whh  = (const float*)d_in[3];
    const float* b_hh = (const float*)d_in[4];
    const float* Why  = (const float*)d_in[5];
    const float* b_y  = (const float*)d_in[6];
    float* out = (float*)d_out;

    char* ws = (char*)d_ws;                       // ~144 MB used
    __hip_bfloat16* WhhT_hi = (__hip_bfloat16*)(ws);
    __hip_bfloat16* WhhT_lo = (__hip_bfloat16*)(ws + (2u  << 20));
    __hip_bfloat16* WxhT_hi = (__hip_bfloat16*)(ws + (4u  << 20));
    __hip_bfloat16* WxhT_lo = (__hip_bfloat16*)(ws + (5u  << 20));
    __hip_bfloat16* h0      = (__hip_bfloat16*)(ws + (6u  << 20));
    __hip_bfloat16* h1      = (__hip_bfloat16*)(ws + (8u  << 20));
    unsigned*       bar     = (unsigned*)      (ws + (10u << 20));
    __hip_bfloat16* xs      = (__hip_bfloat16*)(ws + (16u << 20));  // 128 MB

    prep_kernel<<<384, 256, 0, stream>>>(Whh, Wxh, WhhT_hi, WhhT_lo, WxhT_hi, WxhT_lo);
    convx_all_kernel<<<32768, 256, 0, stream>>>(x, xs);
    zero_kernel<<<513, 256, 0, stream>>>(h0, bar);

    rnn_kernel<<<256, 256, 0, stream>>>(h0, h1, xs,
                                        WhhT_hi, WhhT_lo, WxhT_hi, WxhT_lo,
                                        b_xh, b_hh, bar);

    out_kernel<<<1024, 64, 0, stream>>>(h0, Why, b_y, out);  // final h is in h0
}

// Round 5
// 3098.357 us; speedup vs baseline: 1.0195x; 1.0195x over previous
//
#include <hip/hip_runtime.h>
#include <hip/hip_bf16.h>

#define TT    128
#define BATCH 1024
#define INDIM 512
#define HIDD  1024
#define NCLS  10

typedef __bf16 bf16x8 __attribute__((ext_vector_type(8)));
typedef float  f32x4  __attribute__((ext_vector_type(4)));
typedef unsigned short u16x8 __attribute__((ext_vector_type(8)));

__device__ __forceinline__ unsigned short bf16b(float f) {
    __hip_bfloat16 h = __float2bfloat16(f);
    return __builtin_bit_cast(unsigned short, h);
}

__device__ __forceinline__ float tanh_fast(float x) {
    float e = __expf(2.0f * x);
    return 1.0f - 2.0f * __builtin_amdgcn_rcpf(e + 1.0f);
}

#define WAITV(n) asm volatile("s_waitcnt vmcnt(" #n ")" ::: "memory")
#define BAR()    asm volatile("s_barrier" ::: "memory")

// ---------------------------------------------------------------------------
// Prep: W -> transposed bf16 hi/lo pairs (unchanged, verified R1-R3).
// ---------------------------------------------------------------------------
__global__ __launch_bounds__(256) void prep_kernel(
    const float* __restrict__ Whh, const float* __restrict__ Wxh,
    __hip_bfloat16* __restrict__ WhhT_hi, __hip_bfloat16* __restrict__ WhhT_lo,
    __hip_bfloat16* __restrict__ WxhT_hi, __hip_bfloat16* __restrict__ WxhT_lo)
{
    __shared__ float tl[64][68];
    int bid = blockIdx.x, tid = threadIdx.x;
    const float* src; int N, k0, n0, dstride;
    __hip_bfloat16 *dhi, *dlo;
    if (bid < 256) { src = Whh; N = 1024; k0 = (bid >> 4) << 6; n0 = (bid & 15) << 6;
                     dhi = WhhT_hi; dlo = WhhT_lo; dstride = 1024; }
    else { int b = bid - 256; src = Wxh; N = 1024; k0 = (b >> 4) << 6; n0 = (b & 15) << 6;
           dhi = WxhT_hi; dlo = WxhT_lo; dstride = 512; }

    int r = tid >> 2, c0 = (tid & 3) << 4;
    const float* s = src + (size_t)(k0 + r) * N + n0 + c0;
#pragma unroll
    for (int j = 0; j < 4; ++j)
        *(float4*)&tl[r][c0 + j * 4] = *(const float4*)(s + j * 4);
    __syncthreads();

    int rn = tid >> 2, ck0 = (tid & 3) << 4;
    u16x8 hi0, hi1, lo0, lo1;
#pragma unroll
    for (int j = 0; j < 16; ++j) {
        float w = tl[ck0 + j][rn];
        unsigned short hb = bf16b(w);
        float hf = __bfloat162float(__builtin_bit_cast(__hip_bfloat16, hb));
        unsigned short lb = bf16b(w - hf);
        if (j < 8) { hi0[j] = hb; lo0[j] = lb; }
        else       { hi1[j - 8] = hb; lo1[j - 8] = lb; }
    }
    size_t o = (size_t)(n0 + rn) * dstride + k0 + ck0;
    *(u16x8*)(void*)(dhi + o)     = hi0;
    *(u16x8*)(void*)(dhi + o + 8) = hi1;
    *(u16x8*)(void*)(dlo + o)     = lo0;
    *(u16x8*)(void*)(dlo + o + 8) = lo1;
}

// ---------------------------------------------------------------------------
__global__ __launch_bounds__(256) void convx_all_kernel(
    const float* __restrict__ x, __hip_bfloat16* __restrict__ xs)
{
    size_t gid = (size_t)blockIdx.x * 256 + threadIdx.x;
    int i  = (int)(gid & 63) << 3;
    size_t bt = gid >> 6;
    int t = (int)(bt & 127);
    int b = (int)(bt >> 7);
    const float* s = x + ((size_t)b * TT + t) * INDIM + i;
    float4 a0 = *(const float4*)s, a1 = *(const float4*)(s + 4);
    u16x8 o;
    o[0]=bf16b(a0.x); o[1]=bf16b(a0.y); o[2]=bf16b(a0.z); o[3]=bf16b(a0.w);
    o[4]=bf16b(a1.x); o[5]=bf16b(a1.y); o[6]=bf16b(a1.z); o[7]=bf16b(a1.w);
    *(u16x8*)(void*)(xs + ((size_t)t * BATCH + b) * INDIM + i) = o;
}

__global__ __launch_bounds__(256) void zero_kernel(
    __hip_bfloat16* __restrict__ h, unsigned* __restrict__ bar)
{
    if (blockIdx.x < 512) {
        size_t i = ((size_t)blockIdx.x * 256 + threadIdx.x) << 3;
        u16x8 z = {0,0,0,0,0,0,0,0};
        *(u16x8*)(void*)(h + i) = z;
    } else {
        uint4 z = {0,0,0,0};
        ((uint4*)bar)[threadIdx.x] = z;
    }
}

// ---------------------------------------------------------------------------
// Persistent RNN. 256 blocks x 4 waves. Weights in registers (compiler may
// use AGPRs - proven correct in R3). Per step: [x-phase | join peers (spin
// hidden by x) | h-phase | epilogue | release(atomicAdd)]. Staging: 4x16KB
// LDS bufs, counted vmcnt, raw s_barrier inside phases; __syncthreads at
// the two sync points (free: vmcnt already 0 there).
// ---------------------------------------------------------------------------
#define FRAGA(_b, m, ks) \
    (*(const bf16x8*)((_b) + ((((m)<<4)+ar) << 8) + ((((((ks)<<2)+kg)) ^ (ar & 7)) << 4)))

#define STAGE(basePtr, rs, bufidx) do {                                        \
    _Pragma("unroll")                                                          \
    for (int _i = 0; _i < 4; ++_i) {                                           \
        int _r = (_i << 4) + (tid >> 4);                                       \
        int _s = (tid & 15) ^ (_r & 7);                                        \
        const void* _g = (const void*)((basePtr) + (size_t)_r * (rs) + (_s << 3)); \
        void* _l = (void*)(smem + ((bufidx) << 14) + (_i << 12) + (wave << 10));   \
        __builtin_amdgcn_global_load_lds(                                      \
            (const __attribute__((address_space(1))) void*)_g,                 \
            (__attribute__((address_space(3))) void*)_l, 16, 0, 0);            \
    } } while (0)

#define DO_CHUNK(B_ARR, q, bufidx) do {                                        \
    const char* _b = smem + ((bufidx) << 14);                                  \
    _Pragma("unroll")                                                          \
    for (int ks = 0; ks < 4; ++ks) {                                           \
        bf16x8 a0 = FRAGA(_b, 0, ks), a1 = FRAGA(_b, 1, ks);                   \
        bf16x8 a2 = FRAGA(_b, 2, ks), a3 = FRAGA(_b, 3, ks);                   \
        bf16x8 bh = B_ARR[(q)*8+ks*2+0], bl = B_ARR[(q)*8+ks*2+1];             \
        acc0 = __builtin_amdgcn_mfma_f32_16x16x32_bf16(a0, bh, acc0, 0,0,0);   \
        acc1 = __builtin_amdgcn_mfma_f32_16x16x32_bf16(a1, bh, acc1, 0,0,0);   \
        acc2 = __builtin_amdgcn_mfma_f32_16x16x32_bf16(a2, bh, acc2, 0,0,0);   \
        acc3 = __builtin_amdgcn_mfma_f32_16x16x32_bf16(a3, bh, acc3, 0,0,0);   \
        acc0 = __builtin_amdgcn_mfma_f32_16x16x32_bf16(a0, bl, acc0, 0,0,0);   \
        acc1 = __builtin_amdgcn_mfma_f32_16x16x32_bf16(a1, bl, acc1, 0,0,0);   \
        acc2 = __builtin_amdgcn_mfma_f32_16x16x32_bf16(a2, bl, acc2, 0,0,0);   \
        acc3 = __builtin_amdgcn_mfma_f32_16x16x32_bf16(a3, bl, acc3, 0,0,0);   \
    } } while (0)

__global__ __launch_bounds__(256, 1) void rnn_kernel(
    __hip_bfloat16* __restrict__ h0, __hip_bfloat16* __restrict__ h1,
    const __hip_bfloat16* __restrict__ xs,
    const __hip_bfloat16* __restrict__ WhhT_hi, const __hip_bfloat16* __restrict__ WhhT_lo,
    const __hip_bfloat16* __restrict__ WxhT_hi, const __hip_bfloat16* __restrict__ WxhT_lo,
    const float* __restrict__ b_xh, const float* __restrict__ b_hh,
    unsigned* __restrict__ bar)
{
    __shared__ char smem[65536];                 // 4 x 16KB staging buffers
    int tid = threadIdx.x, bid = blockIdx.x;
    int xcd = bid & 7, idx = bid >> 3;
    int bx = (xcd << 1) | (idx >> 4), by = idx & 15;
    int lane = tid & 63, wave = tid >> 6;
    int ar = lane & 15, kg = lane >> 4;
    int wcol = (bx << 6) + (wave << 4);
    int by64 = by << 6;

    // ---- weights to registers: Whh 64 frags + Wxh 32 frags per wave ----
    bf16x8 Bh[64], Bx[32];
    {
        const __hip_bfloat16* hiB = WhhT_hi + (size_t)(wcol + ar) * HIDD + (kg << 3);
        const __hip_bfloat16* loB = WhhT_lo + (size_t)(wcol + ar) * HIDD + (kg << 3);
#pragma unroll
        for (int c = 0; c < 8; ++c)
#pragma unroll
            for (int ks = 0; ks < 4; ++ks) {
                Bh[c*8 + ks*2 + 0] = *(const bf16x8*)(hiB + c*128 + ks*32);
                Bh[c*8 + ks*2 + 1] = *(const bf16x8*)(loB + c*128 + ks*32);
            }
        const __hip_bfloat16* hiX = WxhT_hi + (size_t)(wcol + ar) * INDIM + (kg << 3);
        const __hip_bfloat16* loX = WxhT_lo + (size_t)(wcol + ar) * INDIM + (kg << 3);
#pragma unroll
        for (int c = 0; c < 4; ++c)
#pragma unroll
            for (int ks = 0; ks < 4; ++ks) {
                Bx[c*8 + ks*2 + 0] = *(const bf16x8*)(hiX + c*128 + ks*32);
                Bx[c*8 + ks*2 + 1] = *(const bf16x8*)(loX + c*128 + ks*32);
            }
    }
    int mycol = wcol + ar;
    float bias = b_xh[mycol] + b_hh[mycol];
    WAITV(0);                                    // retire all prologue loads

    unsigned* myctr = bar + (by << 5);           // per-group counter, 128B apart

    for (int t = 0; t < TT; ++t) {
        const __hip_bfloat16* hA = (t & 1) ? h1 : h0;
        __hip_bfloat16*       hB = (t & 1) ? h0 : h1;
        const __hip_bfloat16* xA = xs + (size_t)t * (BATCH * INDIM) + (size_t)by64 * INDIM;
        const __hip_bfloat16* hR = hA + (size_t)by64 * HIDD;

        f32x4 acc0 = {0,0,0,0}, acc1 = {0,0,0,0}, acc2 = {0,0,0,0}, acc3 = {0,0,0,0};

        // ================= x phase (independent of h_prev) =================
        STAGE(xA + 0*128, INDIM, 0);
        STAGE(xA + 1*128, INDIM, 1);
        STAGE(xA + 2*128, INDIM, 2);
        WAITV(8); BAR();
        DO_CHUNK(Bx, 0, 0);
        STAGE(xA + 3*128, INDIM, 3);
        WAITV(8); BAR();
        DO_CHUNK(Bx, 1, 1);
        WAITV(4); BAR();
        DO_CHUNK(Bx, 2, 2);
        WAITV(0); BAR();
        DO_CHUNK(Bx, 3, 3);

        // ====== join peers' step t-1 (R3-proven protocol, spin hidden) =====
        if (t > 0) {
            if (tid == 0) {
                unsigned target = (unsigned)(t << 4);
                while (__hip_atomic_load(myctr, __ATOMIC_RELAXED,
                                         __HIP_MEMORY_SCOPE_AGENT) < target)
                    __builtin_amdgcn_s_sleep(1);
                __threadfence();                 // acquire: inv stale caches
            }
            __syncthreads();
        }

        // ========================= h phase =================================
        STAGE(hR + 0*128, HIDD, 0);
        STAGE(hR + 1*128, HIDD, 1);
        STAGE(hR + 2*128, HIDD, 2);
        WAITV(8); BAR(); DO_CHUNK(Bh, 0, 0);
        STAGE(hR + 3*128, HIDD, 3);
        WAITV(8); BAR(); DO_CHUNK(Bh, 1, 1);
        STAGE(hR + 4*128, HIDD, 0);
        WAITV(8); BAR(); DO_CHUNK(Bh, 2, 2);
        STAGE(hR + 5*128, HIDD, 1);
        WAITV(8); BAR(); DO_CHUNK(Bh, 3, 3);
        STAGE(hR + 6*128, HIDD, 2);
        WAITV(8); BAR(); DO_CHUNK(Bh, 4, 0);
        STAGE(hR + 7*128, HIDD, 3);
        WAITV(8); BAR(); DO_CHUNK(Bh, 5, 1);
        WAITV(4); BAR(); DO_CHUNK(Bh, 6, 2);
        WAITV(0); BAR(); DO_CHUNK(Bh, 7, 3);

        // ===================== epilogue + release ==========================
#pragma unroll
        for (int m = 0; m < 4; ++m) {
            f32x4 a = (m == 0) ? acc0 : (m == 1) ? acc1 : (m == 2) ? acc2 : acc3;
#pragma unroll
            for (int j = 0; j < 4; ++j) {
                int row = by64 + (m << 4) + (kg << 2) + j;
                float v = tanh_fast(a[j] + bias);
                hB[(size_t)row * HIDD + mycol] = __float2bfloat16(v);
            }
        }
        __syncthreads();                         // drains stores (vmcnt 0)
        if (t < TT - 1 && tid == 0) {
            __threadfence();                     // release
            atomicAdd(myctr, 1u);
        }
    }
}

// ---------------------------------------------------------------------------
__global__ __launch_bounds__(64) void out_kernel(
    const __hip_bfloat16* __restrict__ h, const float* __restrict__ Why,
    const float* __restrict__ b_y, float* __restrict__ out)
{
    int b = blockIdx.x, lane = threadIdx.x;
    float acc[NCLS];
#pragma unroll
    for (int c = 0; c < NCLS; ++c) acc[c] = 0.f;
    for (int kk = 0; kk < 16; ++kk) {
        int k = (kk << 6) + lane;
        float hv = __bfloat162float(h[(size_t)b * HIDD + k]);
#pragma unroll
        for (int c = 0; c < NCLS; ++c) acc[c] += hv * Why[(size_t)k * NCLS + c];
    }
#pragma unroll
    for (int c = 0; c < NCLS; ++c) {
        float v = acc[c];
#pragma unroll
        for (int off = 32; off > 0; off >>= 1) v += __shfl_down(v, off);
        if (lane == 0) out[(size_t)b * NCLS + c] = v + b_y[c];
    }
}

// ---------------------------------------------------------------------------
extern "C" void kernel_launch(void* const* d_in, const int* in_sizes, int n_in,
                              void* d_out, int out_size, void* d_ws, size_t ws_size,
                              hipStream_t stream)
{
    const float* x    = (const float*)d_in[0];
    const float* Wxh  = (const float*)d_in[1];
    const float* b_xh = (const float*)d_in[2];
    const float* Whh  = (const float*)d_in[3];
    const float* b_hh = (const float*)d_in[4];
    const float* Why  = (const float*)d_in[5];
    const float* b_y  = (const float*)d_in[6];
    float* out = (float*)d_out;

    char* ws = (char*)d_ws;                       // 144 MB used
    __hip_bfloat16* WhhT_hi = (__hip_bfloat16*)(ws);
    __hip_bfloat16* WhhT_lo = (__hip_bfloat16*)(ws + (2u  << 20));
    __hip_bfloat16* WxhT_hi = (__hip_bfloat16*)(ws + (4u  << 20));
    __hip_bfloat16* WxhT_lo = (__hip_bfloat16*)(ws + (5u  << 20));
    __hip_bfloat16* h0      = (__hip_bfloat16*)(ws + (6u  << 20));
    __hip_bfloat16* h1      = (__hip_bfloat16*)(ws + (8u  << 20));
    unsigned*       bar     = (unsigned*)      (ws + (10u << 20));
    __hip_bfloat16* xs      = (__hip_bfloat16*)(ws + (16u << 20));  // 128 MB

    prep_kernel<<<384, 256, 0, stream>>>(Whh, Wxh, WhhT_hi, WhhT_lo, WxhT_hi, WxhT_lo);
    convx_all_kernel<<<32768, 256, 0, stream>>>(x, xs);
    zero_kernel<<<513, 256, 0, stream>>>(h0, bar);

    rnn_kernel<<<256, 256, 0, stream>>>(h0, h1, xs,
                                        WhhT_hi, WhhT_lo, WxhT_hi, WxhT_lo,
                                        b_xh, b_hh, bar);

    out_kernel<<<1024, 64, 0, stream>>>(h0, Why, b_y, out);  // final h is in h0
}

// Round 6
// 1154.725 us; speedup vs baseline: 2.7354x; 2.6832x over previous
//
#include <hip/hip_runtime.h>
#include <hip/hip_bf16.h>

#define TT    128
#define BATCH 1024
#define INDIM 512
#define HIDD  1024
#define NCLS  10

typedef __bf16 bf16x8 __attribute__((ext_vector_type(8)));
typedef float  f32x4  __attribute__((ext_vector_type(4)));
typedef unsigned short u16x8 __attribute__((ext_vector_type(8)));

__device__ __forceinline__ unsigned short bf16b(float f) {
    __hip_bfloat16 h = __float2bfloat16(f);
    return __builtin_bit_cast(unsigned short, h);
}

__device__ __forceinline__ float tanh_fast(float x) {
    float e = __expf(2.0f * x);
    return 1.0f - 2.0f * __builtin_amdgcn_rcpf(e + 1.0f);
}

#define WAITV(n) asm volatile("s_waitcnt vmcnt(" #n ")" ::: "memory")
#define BAR()    asm volatile("s_barrier" ::: "memory")

// ---------------------------------------------------------------------------
// Prep: W -> transposed bf16 hi/lo pairs (unchanged, verified R1-R5).
// ---------------------------------------------------------------------------
__global__ __launch_bounds__(256) void prep_kernel(
    const float* __restrict__ Whh, const float* __restrict__ Wxh,
    __hip_bfloat16* __restrict__ WhhT_hi, __hip_bfloat16* __restrict__ WhhT_lo,
    __hip_bfloat16* __restrict__ WxhT_hi, __hip_bfloat16* __restrict__ WxhT_lo)
{
    __shared__ float tl[64][68];
    int bid = blockIdx.x, tid = threadIdx.x;
    const float* src; int N, k0, n0, dstride;
    __hip_bfloat16 *dhi, *dlo;
    if (bid < 256) { src = Whh; N = 1024; k0 = (bid >> 4) << 6; n0 = (bid & 15) << 6;
                     dhi = WhhT_hi; dlo = WhhT_lo; dstride = 1024; }
    else { int b = bid - 256; src = Wxh; N = 1024; k0 = (b >> 4) << 6; n0 = (b & 15) << 6;
           dhi = WxhT_hi; dlo = WxhT_lo; dstride = 512; }

    int r = tid >> 2, c0 = (tid & 3) << 4;
    const float* s = src + (size_t)(k0 + r) * N + n0 + c0;
#pragma unroll
    for (int j = 0; j < 4; ++j)
        *(float4*)&tl[r][c0 + j * 4] = *(const float4*)(s + j * 4);
    __syncthreads();

    int rn = tid >> 2, ck0 = (tid & 3) << 4;
    u16x8 hi0, hi1, lo0, lo1;
#pragma unroll
    for (int j = 0; j < 16; ++j) {
        float w = tl[ck0 + j][rn];
        unsigned short hb = bf16b(w);
        float hf = __bfloat162float(__builtin_bit_cast(__hip_bfloat16, hb));
        unsigned short lb = bf16b(w - hf);
        if (j < 8) { hi0[j] = hb; lo0[j] = lb; }
        else       { hi1[j - 8] = hb; lo1[j - 8] = lb; }
    }
    size_t o = (size_t)(n0 + rn) * dstride + k0 + ck0;
    *(u16x8*)(void*)(dhi + o)     = hi0;
    *(u16x8*)(void*)(dhi + o + 8) = hi1;
    *(u16x8*)(void*)(dlo + o)     = lo0;
    *(u16x8*)(void*)(dlo + o + 8) = lo1;
}

// ---------------------------------------------------------------------------
__global__ __launch_bounds__(256) void convx_all_kernel(
    const float* __restrict__ x, __hip_bfloat16* __restrict__ xs)
{
    size_t gid = (size_t)blockIdx.x * 256 + threadIdx.x;
    int i  = (int)(gid & 63) << 3;
    size_t bt = gid >> 6;
    int t = (int)(bt & 127);
    int b = (int)(bt >> 7);
    const float* s = x + ((size_t)b * TT + t) * INDIM + i;
    float4 a0 = *(const float4*)s, a1 = *(const float4*)(s + 4);
    u16x8 o;
    o[0]=bf16b(a0.x); o[1]=bf16b(a0.y); o[2]=bf16b(a0.z); o[3]=bf16b(a0.w);
    o[4]=bf16b(a1.x); o[5]=bf16b(a1.y); o[6]=bf16b(a1.z); o[7]=bf16b(a1.w);
    *(u16x8*)(void*)(xs + ((size_t)t * BATCH + b) * INDIM + i) = o;
}

__global__ __launch_bounds__(256) void zero_kernel(
    __hip_bfloat16* __restrict__ h, unsigned* __restrict__ bar)
{
    if (blockIdx.x < 512) {
        size_t i = ((size_t)blockIdx.x * 256 + threadIdx.x) << 3;
        u16x8 z = {0,0,0,0,0,0,0,0};
        *(u16x8*)(void*)(h + i) = z;
    } else {
        uint4 z = {0,0,0,0};
#pragma unroll
        for (int k = 0; k < 8; ++k)              // 32 KB of flags
            ((uint4*)bar)[k * 256 + threadIdx.x] = z;
    }
}

// ---------------------------------------------------------------------------
// Persistent RNN, R6: by-groups are XCD-local (bid%8 -> XCD, so group =
// {bid : bid&7==by&7, (bid>>3)&1==by>>3} all on one XCD). h exchange stays in
// that XCD's L2 (L1 is write-through; __syncthreads drains stores to L2).
// h staging uses sc0 (aux=1) to bypass possibly-stale L1. No fences anywhere.
// Sync: per-block flag words (128B apart), release = relaxed SYSTEM store,
// poll = 16 parallel lane loads, hidden behind the h-independent x-phase.
// ---------------------------------------------------------------------------
#define FRAGA(_b, m, ks) \
    (*(const bf16x8*)((_b) + ((((m)<<4)+ar) << 8) + ((((((ks)<<2)+kg)) ^ (ar & 7)) << 4)))

#define STAGE(basePtr, rs, bufidx, AUX) do {                                   \
    _Pragma("unroll")                                                          \
    for (int _i = 0; _i < 4; ++_i) {                                           \
        int _r = (_i << 4) + (tid >> 4);                                       \
        int _s = (tid & 15) ^ (_r & 7);                                        \
        const void* _g = (const void*)((basePtr) + (size_t)_r * (rs) + (_s << 3)); \
        void* _l = (void*)(smem + ((bufidx) << 14) + (_i << 12) + (wave << 10));   \
        __builtin_amdgcn_global_load_lds(                                      \
            (const __attribute__((address_space(1))) void*)_g,                 \
            (__attribute__((address_space(3))) void*)_l, 16, 0, AUX);          \
    } } while (0)

#define DO_CHUNK(B_ARR, q, bufidx) do {                                        \
    const char* _b = smem + ((bufidx) << 14);                                  \
    _Pragma("unroll")                                                          \
    for (int ks = 0; ks < 4; ++ks) {                                           \
        bf16x8 a0 = FRAGA(_b, 0, ks), a1 = FRAGA(_b, 1, ks);                   \
        bf16x8 a2 = FRAGA(_b, 2, ks), a3 = FRAGA(_b, 3, ks);                   \
        bf16x8 bh = B_ARR[(q)*8+ks*2+0], bl = B_ARR[(q)*8+ks*2+1];             \
        acc0 = __builtin_amdgcn_mfma_f32_16x16x32_bf16(a0, bh, acc0, 0,0,0);   \
        acc1 = __builtin_amdgcn_mfma_f32_16x16x32_bf16(a1, bh, acc1, 0,0,0);   \
        acc2 = __builtin_amdgcn_mfma_f32_16x16x32_bf16(a2, bh, acc2, 0,0,0);   \
        acc3 = __builtin_amdgcn_mfma_f32_16x16x32_bf16(a3, bh, acc3, 0,0,0);   \
        acc0 = __builtin_amdgcn_mfma_f32_16x16x32_bf16(a0, bl, acc0, 0,0,0);   \
        acc1 = __builtin_amdgcn_mfma_f32_16x16x32_bf16(a1, bl, acc1, 0,0,0);   \
        acc2 = __builtin_amdgcn_mfma_f32_16x16x32_bf16(a2, bl, acc2, 0,0,0);   \
        acc3 = __builtin_amdgcn_mfma_f32_16x16x32_bf16(a3, bl, acc3, 0,0,0);   \
    } } while (0)

__global__ __launch_bounds__(256, 1) void rnn_kernel(
    __hip_bfloat16* __restrict__ h0, __hip_bfloat16* __restrict__ h1,
    const __hip_bfloat16* __restrict__ xs,
    const __hip_bfloat16* __restrict__ WhhT_hi, const __hip_bfloat16* __restrict__ WhhT_lo,
    const __hip_bfloat16* __restrict__ WxhT_hi, const __hip_bfloat16* __restrict__ WxhT_lo,
    const float* __restrict__ b_xh, const float* __restrict__ b_hh,
    unsigned* __restrict__ bar)
{
    __shared__ char smem[65536];                 // 4 x 16KB staging buffers
    int tid = threadIdx.x, bid = blockIdx.x;
    // XCD-local by-groups: bid%8 = XCD; group members share bid&7 and bit3.
    int by = (bid & 7) | (((bid >> 3) & 1) << 3);
    int bx = bid >> 4;
    int lane = tid & 63, wave = tid >> 6;
    int ar = lane & 15, kg = lane >> 4;
    int wcol = (bx << 6) + (wave << 4);
    int by64 = by << 6;

    // ---- weights to registers: Whh 64 frags + Wxh 32 frags per wave ----
    bf16x8 Bh[64], Bx[32];
    {
        const __hip_bfloat16* hiB = WhhT_hi + (size_t)(wcol + ar) * HIDD + (kg << 3);
        const __hip_bfloat16* loB = WhhT_lo + (size_t)(wcol + ar) * HIDD + (kg << 3);
#pragma unroll
        for (int c = 0; c < 8; ++c)
#pragma unroll
            for (int ks = 0; ks < 4; ++ks) {
                Bh[c*8 + ks*2 + 0] = *(const bf16x8*)(hiB + c*128 + ks*32);
                Bh[c*8 + ks*2 + 1] = *(const bf16x8*)(loB + c*128 + ks*32);
            }
        const __hip_bfloat16* hiX = WxhT_hi + (size_t)(wcol + ar) * INDIM + (kg << 3);
        const __hip_bfloat16* loX = WxhT_lo + (size_t)(wcol + ar) * INDIM + (kg << 3);
#pragma unroll
        for (int c = 0; c < 4; ++c)
#pragma unroll
            for (int ks = 0; ks < 4; ++ks) {
                Bx[c*8 + ks*2 + 0] = *(const bf16x8*)(hiX + c*128 + ks*32);
                Bx[c*8 + ks*2 + 1] = *(const bf16x8*)(loX + c*128 + ks*32);
            }
    }
    int mycol = wcol + ar;
    float bias = b_xh[mycol] + b_hh[mycol];
    WAITV(0);                                    // retire prologue loads

    unsigned* grpflags = bar + (by << 9);        // 16 words x 128B per group
    unsigned* myflag   = grpflags + (bx << 5);

    for (int t = 0; t < TT; ++t) {
        const __hip_bfloat16* hA = (t & 1) ? h1 : h0;
        __hip_bfloat16*       hB = (t & 1) ? h0 : h1;
        const __hip_bfloat16* xA = xs + (size_t)t * (BATCH * INDIM) + (size_t)by64 * INDIM;
        const __hip_bfloat16* hR = hA + (size_t)by64 * HIDD;

        f32x4 acc0 = {0,0,0,0}, acc1 = {0,0,0,0}, acc2 = {0,0,0,0}, acc3 = {0,0,0,0};

        // ============ x phase (independent of h_prev; xs immutable) ========
        STAGE(xA + 0*128, INDIM, 0, 0);
        STAGE(xA + 1*128, INDIM, 1, 0);
        STAGE(xA + 2*128, INDIM, 2, 0);
        WAITV(8); BAR();
        DO_CHUNK(Bx, 0, 0);
        STAGE(xA + 3*128, INDIM, 3, 0);
        WAITV(8); BAR();
        DO_CHUNK(Bx, 1, 1);
        WAITV(4); BAR();
        DO_CHUNK(Bx, 2, 2);
        WAITV(0); BAR();
        DO_CHUNK(Bx, 3, 3);

        // ===== join peers' step t-1 (parallel flag poll, hidden by x) ======
        if (t > 0) {
            if (wave == 0) {
                unsigned tgt = (unsigned)t;
                for (;;) {
                    unsigned v = tgt;
                    if (lane < 16)
                        v = __hip_atomic_load(grpflags + (lane << 5), __ATOMIC_RELAXED,
                                              __HIP_MEMORY_SCOPE_SYSTEM);
                    if (__all(v >= tgt)) break;
                    __builtin_amdgcn_s_sleep(1);
                }
            }
            BAR();
        }

        // ========== h phase (sc0: bypass L1, read group's L2) ==============
        STAGE(hR + 0*128, HIDD, 0, 1);
        STAGE(hR + 1*128, HIDD, 1, 1);
        STAGE(hR + 2*128, HIDD, 2, 1);
        WAITV(8); BAR(); DO_CHUNK(Bh, 0, 0);
        STAGE(hR + 3*128, HIDD, 3, 1);
        WAITV(8); BAR(); DO_CHUNK(Bh, 1, 1);
        STAGE(hR + 4*128, HIDD, 0, 1);
        WAITV(8); BAR(); DO_CHUNK(Bh, 2, 2);
        STAGE(hR + 5*128, HIDD, 1, 1);
        WAITV(8); BAR(); DO_CHUNK(Bh, 3, 3);
        STAGE(hR + 6*128, HIDD, 2, 1);
        WAITV(8); BAR(); DO_CHUNK(Bh, 4, 0);
        STAGE(hR + 7*128, HIDD, 3, 1);
        WAITV(8); BAR(); DO_CHUNK(Bh, 5, 1);
        WAITV(4); BAR(); DO_CHUNK(Bh, 6, 2);
        WAITV(0); BAR(); DO_CHUNK(Bh, 7, 3);

        // ===================== epilogue + release ==========================
#pragma unroll
        for (int m = 0; m < 4; ++m) {
            f32x4 a = (m == 0) ? acc0 : (m == 1) ? acc1 : (m == 2) ? acc2 : acc3;
#pragma unroll
            for (int j = 0; j < 4; ++j) {
                int row = by64 + (m << 4) + (kg << 2) + j;
                float v = tanh_fast(a[j] + bias);
                hB[(size_t)row * HIDD + mycol] = __float2bfloat16(v);
            }
        }
        __syncthreads();                         // drains h stores to L2
        if (t < TT - 1 && tid == 0)
            __hip_atomic_store(myflag, (unsigned)(t + 1), __ATOMIC_RELAXED,
                               __HIP_MEMORY_SCOPE_SYSTEM);
    }
}

// ---------------------------------------------------------------------------
__global__ __launch_bounds__(64) void out_kernel(
    const __hip_bfloat16* __restrict__ h, const float* __restrict__ Why,
    const float* __restrict__ b_y, float* __restrict__ out)
{
    int b = blockIdx.x, lane = threadIdx.x;
    float acc[NCLS];
#pragma unroll
    for (int c = 0; c < NCLS; ++c) acc[c] = 0.f;
    for (int kk = 0; kk < 16; ++kk) {
        int k = (kk << 6) + lane;
        float hv = __bfloat162float(h[(size_t)b * HIDD + k]);
#pragma unroll
        for (int c = 0; c < NCLS; ++c) acc[c] += hv * Why[(size_t)k * NCLS + c];
    }
#pragma unroll
    for (int c = 0; c < NCLS; ++c) {
        float v = acc[c];
#pragma unroll
        for (int off = 32; off > 0; off >>= 1) v += __shfl_down(v, off);
        if (lane == 0) out[(size_t)b * NCLS + c] = v + b_y[c];
    }
}

// ---------------------------------------------------------------------------
extern "C" void kernel_launch(void* const* d_in, const int* in_sizes, int n_in,
                              void* d_out, int out_size, void* d_ws, size_t ws_size,
                              hipStream_t stream)
{
    const float* x    = (const float*)d_in[0];
    const float* Wxh  = (const float*)d_in[1];
    const float* b_xh = (const float*)d_in[2];
    const float* Whh  = (const float*)d_in[3];
    const float* b_hh = (const float*)d_in[4];
    const float* Why  = (const float*)d_in[5];
    const float* b_y  = (const float*)d_in[6];
    float* out = (float*)d_out;

    char* ws = (char*)d_ws;                       // 144 MB used
    __hip_bfloat16* WhhT_hi = (__hip_bfloat16*)(ws);
    __hip_bfloat16* WhhT_lo = (__hip_bfloat16*)(ws + (2u  << 20));
    __hip_bfloat16* WxhT_hi = (__hip_bfloat16*)(ws + (4u  << 20));
    __hip_bfloat16* WxhT_lo = (__hip_bfloat16*)(ws + (5u  << 20));
    __hip_bfloat16* h0      = (__hip_bfloat16*)(ws + (6u  << 20));
    __hip_bfloat16* h1      = (__hip_bfloat16*)(ws + (8u  << 20));
    unsigned*       bar     = (unsigned*)      (ws + (10u << 20));
    __hip_bfloat16* xs      = (__hip_bfloat16*)(ws + (16u << 20));  // 128 MB

    prep_kernel<<<384, 256, 0, stream>>>(Whh, Wxh, WhhT_hi, WhhT_lo, WxhT_hi, WxhT_lo);
    convx_all_kernel<<<32768, 256, 0, stream>>>(x, xs);
    zero_kernel<<<513, 256, 0, stream>>>(h0, bar);

    rnn_kernel<<<256, 256, 0, stream>>>(h0, h1, xs,
                                        WhhT_hi, WhhT_lo, WxhT_hi, WxhT_lo,
                                        b_xh, b_hh, bar);

    out_kernel<<<1024, 64, 0, stream>>>(h0, Why, b_y, out);  // final h is in h0
}

// Round 7
// 881.057 us; speedup vs baseline: 3.5851x; 1.3106x over previous
//
#include <hip/hip_runtime.h>
#include <hip/hip_bf16.h>

#define TT    128
#define BATCH 1024
#define INDIM 512
#define HIDD  1024
#define NCLS  10

typedef __bf16 bf16x8 __attribute__((ext_vector_type(8)));
typedef float  f32x4  __attribute__((ext_vector_type(4)));
typedef unsigned short u16x8 __attribute__((ext_vector_type(8)));

__device__ __forceinline__ unsigned short bf16b(float f) {
    __hip_bfloat16 h = __float2bfloat16(f);
    return __builtin_bit_cast(unsigned short, h);
}

__device__ __forceinline__ float tanh_fast(float x) {
    float e = __expf(2.0f * x);
    return 1.0f - 2.0f * __builtin_amdgcn_rcpf(e + 1.0f);
}

#define WAITV(n) asm volatile("s_waitcnt vmcnt(" #n ")" ::: "memory")
#define BAR()    asm volatile("s_barrier" ::: "memory")

// ---------------------------------------------------------------------------
// Prep: W -> transposed bf16 hi/lo pairs (unchanged, verified R1-R6).
// ---------------------------------------------------------------------------
__global__ __launch_bounds__(256) void prep_kernel(
    const float* __restrict__ Whh, const float* __restrict__ Wxh,
    __hip_bfloat16* __restrict__ WhhT_hi, __hip_bfloat16* __restrict__ WhhT_lo,
    __hip_bfloat16* __restrict__ WxhT_hi, __hip_bfloat16* __restrict__ WxhT_lo)
{
    __shared__ float tl[64][68];
    int bid = blockIdx.x, tid = threadIdx.x;
    const float* src; int N, k0, n0, dstride;
    __hip_bfloat16 *dhi, *dlo;
    if (bid < 256) { src = Whh; N = 1024; k0 = (bid >> 4) << 6; n0 = (bid & 15) << 6;
                     dhi = WhhT_hi; dlo = WhhT_lo; dstride = 1024; }
    else { int b = bid - 256; src = Wxh; N = 1024; k0 = (b >> 4) << 6; n0 = (b & 15) << 6;
           dhi = WxhT_hi; dlo = WxhT_lo; dstride = 512; }

    int r = tid >> 2, c0 = (tid & 3) << 4;
    const float* s = src + (size_t)(k0 + r) * N + n0 + c0;
#pragma unroll
    for (int j = 0; j < 4; ++j)
        *(float4*)&tl[r][c0 + j * 4] = *(const float4*)(s + j * 4);
    __syncthreads();

    int rn = tid >> 2, ck0 = (tid & 3) << 4;
    u16x8 hi0, hi1, lo0, lo1;
#pragma unroll
    for (int j = 0; j < 16; ++j) {
        float w = tl[ck0 + j][rn];
        unsigned short hb = bf16b(w);
        float hf = __bfloat162float(__builtin_bit_cast(__hip_bfloat16, hb));
        unsigned short lb = bf16b(w - hf);
        if (j < 8) { hi0[j] = hb; lo0[j] = lb; }
        else       { hi1[j - 8] = hb; lo1[j - 8] = lb; }
    }
    size_t o = (size_t)(n0 + rn) * dstride + k0 + ck0;
    *(u16x8*)(void*)(dhi + o)     = hi0;
    *(u16x8*)(void*)(dhi + o + 8) = hi1;
    *(u16x8*)(void*)(dlo + o)     = lo0;
    *(u16x8*)(void*)(dlo + o + 8) = lo1;
}

// ---------------------------------------------------------------------------
__global__ __launch_bounds__(256) void convx_all_kernel(
    const float* __restrict__ x, __hip_bfloat16* __restrict__ xs)
{
    size_t gid = (size_t)blockIdx.x * 256 + threadIdx.x;
    int i  = (int)(gid & 63) << 3;
    size_t bt = gid >> 6;
    int t = (int)(bt & 127);
    int b = (int)(bt >> 7);
    const float* s = x + ((size_t)b * TT + t) * INDIM + i;
    float4 a0 = *(const float4*)s, a1 = *(const float4*)(s + 4);
    u16x8 o;
    o[0]=bf16b(a0.x); o[1]=bf16b(a0.y); o[2]=bf16b(a0.z); o[3]=bf16b(a0.w);
    o[4]=bf16b(a1.x); o[5]=bf16b(a1.y); o[6]=bf16b(a1.z); o[7]=bf16b(a1.w);
    *(u16x8*)(void*)(xs + ((size_t)t * BATCH + b) * INDIM + i) = o;
}

__global__ __launch_bounds__(256) void zero_kernel(
    __hip_bfloat16* __restrict__ h, unsigned* __restrict__ bar)
{
    if (blockIdx.x < 512) {
        size_t i = ((size_t)blockIdx.x * 256 + threadIdx.x) << 3;
        u16x8 z = {0,0,0,0,0,0,0,0};
        *(u16x8*)(void*)(h + i) = z;
    } else {
        uint4 z = {0,0,0,0};
#pragma unroll
        for (int k = 0; k < 8; ++k)
            ((uint4*)bar)[k * 256 + threadIdx.x] = z;
    }
}

// ---------------------------------------------------------------------------
// Persistent RNN, R7. 8x16KB LDS bufs, 5 barriers/step, counted vmcnt, and
// x(t+1) DMA'd during step t's h-phase. Buffer map per step:
//   x(t):  x0@b2 x1@b3 x2@b0 x3@b1   (staged during step t-1)
//   h:     h0-3 -> b4-7, h4,5 -> b0,b1, h6,7 re-stage b6,b7
//   x(t+1): x0'->b2 x1'->b3 (early, ~5K cyc flight), x2'->b0 x3'->b1 (late)
// vmcnt ledger (per thread, in-order retire) verified per chunk; t=127
// (no x' staging) uses W8/W0/W0 instead of W16/W8/W0.
// ---------------------------------------------------------------------------
#define FRAGA(_b, m, ks) \
    (*(const bf16x8*)((_b) + ((((m)<<4)+ar) << 8) + ((((((ks)<<2)+kg)) ^ (ar & 7)) << 4)))

#define STAGE(basePtr, rs, bufidx, AUX) do {                                   \
    _Pragma("unroll")                                                          \
    for (int _i = 0; _i < 4; ++_i) {                                           \
        int _r = (_i << 4) + (tid >> 4);                                       \
        int _s = (tid & 15) ^ (_r & 7);                                        \
        const void* _g = (const void*)((basePtr) + (size_t)_r * (rs) + (_s << 3)); \
        void* _l = (void*)(smem + ((bufidx) << 14) + (_i << 12) + (wave << 10));   \
        __builtin_amdgcn_global_load_lds(                                      \
            (const __attribute__((address_space(1))) void*)_g,                 \
            (__attribute__((address_space(3))) void*)_l, 16, 0, AUX);          \
    } } while (0)

#define DO_CHUNK(B_ARR, q, bufidx) do {                                        \
    const char* _b = smem + ((bufidx) << 14);                                  \
    _Pragma("unroll")                                                          \
    for (int ks = 0; ks < 4; ++ks) {                                           \
        bf16x8 a0 = FRAGA(_b, 0, ks), a1 = FRAGA(_b, 1, ks);                   \
        bf16x8 a2 = FRAGA(_b, 2, ks), a3 = FRAGA(_b, 3, ks);                   \
        bf16x8 bh = B_ARR[(q)*8+ks*2+0], bl = B_ARR[(q)*8+ks*2+1];             \
        acc0 = __builtin_amdgcn_mfma_f32_16x16x32_bf16(a0, bh, acc0, 0,0,0);   \
        acc1 = __builtin_amdgcn_mfma_f32_16x16x32_bf16(a1, bh, acc1, 0,0,0);   \
        acc2 = __builtin_amdgcn_mfma_f32_16x16x32_bf16(a2, bh, acc2, 0,0,0);   \
        acc3 = __builtin_amdgcn_mfma_f32_16x16x32_bf16(a3, bh, acc3, 0,0,0);   \
        acc0 = __builtin_amdgcn_mfma_f32_16x16x32_bf16(a0, bl, acc0, 0,0,0);   \
        acc1 = __builtin_amdgcn_mfma_f32_16x16x32_bf16(a1, bl, acc1, 0,0,0);   \
        acc2 = __builtin_amdgcn_mfma_f32_16x16x32_bf16(a2, bl, acc2, 0,0,0);   \
        acc3 = __builtin_amdgcn_mfma_f32_16x16x32_bf16(a3, bl, acc3, 0,0,0);   \
    } } while (0)

__global__ __launch_bounds__(256, 1) void rnn_kernel(
    __hip_bfloat16* __restrict__ h0, __hip_bfloat16* __restrict__ h1,
    const __hip_bfloat16* __restrict__ xs,
    const __hip_bfloat16* __restrict__ WhhT_hi, const __hip_bfloat16* __restrict__ WhhT_lo,
    const __hip_bfloat16* __restrict__ WxhT_hi, const __hip_bfloat16* __restrict__ WxhT_lo,
    const float* __restrict__ b_xh, const float* __restrict__ b_hh,
    unsigned* __restrict__ bar)
{
    __shared__ char smem[131072];                // 8 x 16KB staging buffers
    int tid = threadIdx.x, bid = blockIdx.x;
    // XCD-local by-groups (proven R6): bid%8 = XCD.
    int by = (bid & 7) | (((bid >> 3) & 1) << 3);
    int bx = bid >> 4;
    int lane = tid & 63, wave = tid >> 6;
    int ar = lane & 15, kg = lane >> 4;
    int wcol = (bx << 6) + (wave << 4);
    int by64 = by << 6;

    // ---- weights to registers: Whh 64 frags (AGPR) + Wxh 32 frags ----
    bf16x8 Bh[64], Bx[32];
    {
        const __hip_bfloat16* hiB = WhhT_hi + (size_t)(wcol + ar) * HIDD + (kg << 3);
        const __hip_bfloat16* loB = WhhT_lo + (size_t)(wcol + ar) * HIDD + (kg << 3);
#pragma unroll
        for (int c = 0; c < 8; ++c)
#pragma unroll
            for (int ks = 0; ks < 4; ++ks) {
                Bh[c*8 + ks*2 + 0] = *(const bf16x8*)(hiB + c*128 + ks*32);
                Bh[c*8 + ks*2 + 1] = *(const bf16x8*)(loB + c*128 + ks*32);
            }
        const __hip_bfloat16* hiX = WxhT_hi + (size_t)(wcol + ar) * INDIM + (kg << 3);
        const __hip_bfloat16* loX = WxhT_lo + (size_t)(wcol + ar) * INDIM + (kg << 3);
#pragma unroll
        for (int c = 0; c < 4; ++c)
#pragma unroll
            for (int ks = 0; ks < 4; ++ks) {
                Bx[c*8 + ks*2 + 0] = *(const bf16x8*)(hiX + c*128 + ks*32);
                Bx[c*8 + ks*2 + 1] = *(const bf16x8*)(loX + c*128 + ks*32);
            }
    }
    int mycol = wcol + ar;
    float bias = b_xh[mycol] + b_hh[mycol];

    unsigned* grpflags = bar + (by << 9);
    unsigned* myflag   = grpflags + (bx << 5);

    // Prologue: stage x(0): x0->b2, x1->b3, x2->b0, x3->b1.
    {
        const __hip_bfloat16* xA0 = xs + (size_t)by64 * INDIM;
        STAGE(xA0 + 0*128, INDIM, 2, 0);
        STAGE(xA0 + 1*128, INDIM, 3, 0);
        STAGE(xA0 + 2*128, INDIM, 0, 0);
        STAGE(xA0 + 3*128, INDIM, 1, 0);
    }
    WAITV(0); BAR();                             // weights + x(0) all in

    for (int t = 0; t < TT; ++t) {
        const __hip_bfloat16* hA = (t & 1) ? h1 : h0;
        __hip_bfloat16*       hB = (t & 1) ? h0 : h1;
        const __hip_bfloat16* hR = hA + (size_t)by64 * HIDD;
        const __hip_bfloat16* xN = xs + (size_t)(t + 1) * (BATCH * INDIM)
                                      + (size_t)by64 * INDIM;   // x(t+1)
        int nl = (t < TT - 1);

        f32x4 acc0 = {0,0,0,0}, acc1 = {0,0,0,0}, acc2 = {0,0,0,0}, acc3 = {0,0,0,0};

        // ===== region 1: x-compute, 4 chunks, barrier-free ==================
        DO_CHUNK(Bx, 0, 2);
        DO_CHUNK(Bx, 1, 3);
        DO_CHUNK(Bx, 2, 0);
        DO_CHUNK(Bx, 3, 1);

        // ===== poll peers' h(t-1) (hidden behind x-compute) =================
        if (t > 0) {
            if (wave == 0) {
                unsigned tgt = (unsigned)t;
                for (;;) {
                    unsigned v = tgt;
                    if (lane < 16)
                        v = __hip_atomic_load(grpflags + (lane << 5), __ATOMIC_RELAXED,
                                              __HIP_MEMORY_SCOPE_SYSTEM);
                    if (__all(v >= tgt)) break;
                    __builtin_amdgcn_s_sleep(1);
                }
            }
        }
        BAR();                                   // also frees b0-b3 / b2,b3

        // ===== h-phase: stage h0-5 + x'(first half), then compute ==========
        STAGE(hR + 0*128, HIDD, 4, 1);
        STAGE(hR + 1*128, HIDD, 5, 1);
        STAGE(hR + 2*128, HIDD, 6, 1);
        STAGE(hR + 3*128, HIDD, 7, 1);
        STAGE(hR + 4*128, HIDD, 0, 1);
        STAGE(hR + 5*128, HIDD, 1, 1);
        if (nl) {
            STAGE(xN + 0*128, INDIM, 2, 0);      // x0' -> b2 (long flight)
            STAGE(xN + 1*128, INDIM, 3, 0);      // x1' -> b3
            WAITV(16);                           // h0-h3 retired (oldest 16)
        } else {
            WAITV(8);                            // 24 out -> oldest 16 = h0-h3
        }
        BAR();
        DO_CHUNK(Bh, 0, 4);                      // 4 chunks barrier-free
        DO_CHUNK(Bh, 1, 5);
        DO_CHUNK(Bh, 2, 6);
        DO_CHUNK(Bh, 3, 7);
        if (nl) { WAITV(8); } else { WAITV(0); } // h4,h5 retired
        BAR();                                   // b6,b7 readers done
        STAGE(hR + 6*128, HIDD, 6, 1);           // re-stage h6,h7
        STAGE(hR + 7*128, HIDD, 7, 1);
        DO_CHUNK(Bh, 4, 0);
        DO_CHUNK(Bh, 5, 1);
        WAITV(0);                                // h6,h7 in (1600cyc flight)
        BAR();                                   // b0,b1 readers done
        if (nl) {
            STAGE(xN + 2*128, INDIM, 0, 0);      // x2' -> b0
            STAGE(xN + 3*128, INDIM, 1, 0);      // x3' -> b1
        }
        DO_CHUNK(Bh, 6, 6);
        DO_CHUNK(Bh, 7, 7);

        // ===== epilogue + release ==========================================
#pragma unroll
        for (int m = 0; m < 4; ++m) {
            f32x4 a = (m == 0) ? acc0 : (m == 1) ? acc1 : (m == 2) ? acc2 : acc3;
#pragma unroll
            for (int j = 0; j < 4; ++j) {
                int row = by64 + (m << 4) + (kg << 2) + j;
                float v = tanh_fast(a[j] + bias);
                hB[(size_t)row * HIDD + mycol] = __float2bfloat16(v);
            }
        }
        WAITV(0);                                // stores + x2',x3' drained
        BAR();                                   // all threads' stores done
        if (nl && tid == 0)
            __hip_atomic_store(myflag, (unsigned)(t + 1), __ATOMIC_RELAXED,
                               __HIP_MEMORY_SCOPE_SYSTEM);
    }
}

// ---------------------------------------------------------------------------
__global__ __launch_bounds__(64) void out_kernel(
    const __hip_bfloat16* __restrict__ h, const float* __restrict__ Why,
    const float* __restrict__ b_y, float* __restrict__ out)
{
    int b = blockIdx.x, lane = threadIdx.x;
    float acc[NCLS];
#pragma unroll
    for (int c = 0; c < NCLS; ++c) acc[c] = 0.f;
    for (int kk = 0; kk < 16; ++kk) {
        int k = (kk << 6) + lane;
        float hv = __bfloat162float(h[(size_t)b * HIDD + k]);
#pragma unroll
        for (int c = 0; c < NCLS; ++c) acc[c] += hv * Why[(size_t)k * NCLS + c];
    }
#pragma unroll
    for (int c = 0; c < NCLS; ++c) {
        float v = acc[c];
#pragma unroll
        for (int off = 32; off > 0; off >>= 1) v += __shfl_down(v, off);
        if (lane == 0) out[(size_t)b * NCLS + c] = v + b_y[c];
    }
}

// ---------------------------------------------------------------------------
extern "C" void kernel_launch(void* const* d_in, const int* in_sizes, int n_in,
                              void* d_out, int out_size, void* d_ws, size_t ws_size,
                              hipStream_t stream)
{
    const float* x    = (const float*)d_in[0];
    const float* Wxh  = (const float*)d_in[1];
    const float* b_xh = (const float*)d_in[2];
    const float* Whh  = (const float*)d_in[3];
    const float* b_hh = (const float*)d_in[4];
    const float* Why  = (const float*)d_in[5];
    const float* b_y  = (const float*)d_in[6];
    float* out = (float*)d_out;

    char* ws = (char*)d_ws;                       // 144 MB used
    __hip_bfloat16* WhhT_hi = (__hip_bfloat16*)(ws);
    __hip_bfloat16* WhhT_lo = (__hip_bfloat16*)(ws + (2u  << 20));
    __hip_bfloat16* WxhT_hi = (__hip_bfloat16*)(ws + (4u  << 20));
    __hip_bfloat16* WxhT_lo = (__hip_bfloat16*)(ws + (5u  << 20));
    __hip_bfloat16* h0      = (__hip_bfloat16*)(ws + (6u  << 20));
    __hip_bfloat16* h1      = (__hip_bfloat16*)(ws + (8u  << 20));
    unsigned*       bar     = (unsigned*)      (ws + (10u << 20));
    __hip_bfloat16* xs      = (__hip_bfloat16*)(ws + (16u << 20));  // 128 MB

    prep_kernel<<<384, 256, 0, stream>>>(Whh, Wxh, WhhT_hi, WhhT_lo, WxhT_hi, WxhT_lo);
    convx_all_kernel<<<32768, 256, 0, stream>>>(x, xs);
    zero_kernel<<<513, 256, 0, stream>>>(h0, bar);

    rnn_kernel<<<256, 256, 0, stream>>>(h0, h1, xs,
                                        WhhT_hi, WhhT_lo, WxhT_hi, WxhT_lo,
                                        b_xh, b_hh, bar);

    out_kernel<<<1024, 64, 0, stream>>>(h0, Why, b_y, out);  // final h is in h0
}